// Round 2
// baseline (472.937 us; speedup 1.0000x reference)
//
#include <hip/hip_runtime.h>

// Problem constants (from reference):
//   table:   [1048576, 64] f32   (268 MB)
//   weights: [67108864, 1] f32   (268 MB)
//   idx0:    [32768, 32] i32
//   idx1:    [32768, 32] i32
//   out:     [32768, 64] f32 = mean over 32 chunks of table[idx0]*weights[idx1]
#define N_B 32768
#define N_CHUNKS 32
#define DIM 64

// Layout: 16 lanes per batch row (each lane owns one float4 of the 64-dim row),
// 256 threads/block => 16 rows/block, grid = 2048 blocks.
//
// Round-2 structure: fully prefetch indices (dependency-free contiguous int4
// loads), then all 32 weight gathers, then a fully-unrolled table-row
// gather/accumulate. Goal: maximize outstanding VMEM per wave (deep vmcnt
// window) instead of re-paying the idx->gather latency chain every 4 chunks.
__global__ __launch_bounds__(256) void WeightedHashEmbedding_kernel(
    const float* __restrict__ table,
    const float* __restrict__ weights,
    const int*   __restrict__ idx0,
    const int*   __restrict__ idx1,
    float*       __restrict__ out)
{
    const int tid  = threadIdx.x;
    const int b    = blockIdx.x * 16 + (tid >> 4);   // batch row for this 16-lane group
    const int quad = tid & 15;                        // which float4 of the 64-dim row

    const int4* p0 = (const int4*)(idx0 + b * N_CHUNKS);
    const int4* p1 = (const int4*)(idx1 + b * N_CHUNKS);

    // ---- Stage 1: prefetch ALL indices (16 contiguous int4 loads, no deps) ----
    int c0[N_CHUNKS];
    int c1[N_CHUNKS];
    #pragma unroll
    for (int g = 0; g < N_CHUNKS / 4; ++g) {
        const int4 t0 = p0[g];
        const int4 t1 = p1[g];
        c0[4 * g + 0] = t0.x; c0[4 * g + 1] = t0.y; c0[4 * g + 2] = t0.z; c0[4 * g + 3] = t0.w;
        c1[4 * g + 0] = t1.x; c1[4 * g + 1] = t1.y; c1[4 * g + 2] = t1.z; c1[4 * g + 3] = t1.w;
    }

    // ---- Stage 2: issue all 32 weight gathers (independent of table gathers) ----
    float w[N_CHUNKS];
    #pragma unroll
    for (int c = 0; c < N_CHUNKS; ++c) {
        w[c] = weights[c1[c]];
    }

    // ---- Stage 3: fully-unrolled table-row gather + accumulate ----
    // Compiler issues gathers ahead and consumes with in-order vmcnt(N) waits,
    // keeping a deep window of 256B row fetches in flight.
    float4 acc = make_float4(0.f, 0.f, 0.f, 0.f);
    #pragma unroll
    for (int c = 0; c < N_CHUNKS; ++c) {
        const float4 v = ((const float4*)(table + (size_t)c0[c] * DIM))[quad];
        acc.x += v.x * w[c];
        acc.y += v.y * w[c];
        acc.z += v.z * w[c];
        acc.w += v.w * w[c];
    }

    const float inv = 1.0f / (float)N_CHUNKS;
    float4 r;
    r.x = acc.x * inv; r.y = acc.y * inv; r.z = acc.z * inv; r.w = acc.w * inv;
    ((float4*)(out + (size_t)b * DIM))[quad] = r;
}

extern "C" void kernel_launch(void* const* d_in, const int* in_sizes, int n_in,
                              void* d_out, int out_size, void* d_ws, size_t ws_size,
                              hipStream_t stream) {
    const float* table   = (const float*)d_in[0];
    const float* weights = (const float*)d_in[1];
    const int*   idx0    = (const int*)d_in[2];
    const int*   idx1    = (const int*)d_in[3];
    float*       out     = (float*)d_out;

    const int rows_per_block = 16;               // 256 threads / 16 lanes per row
    const int grid = N_B / rows_per_block;       // 2048 blocks

    WeightedHashEmbedding_kernel<<<grid, 256, 0, stream>>>(table, weights, idx0, idx1, out);
}